// Round 18
// baseline (264.328 us; speedup 1.0000x reference)
//
#include <hip/hip_runtime.h>
#include <math.h>

// GraphBlock: 2x GATConv(H=2 heads, C=64, concat=False) + BN(train) + GELU + skip + mean-pool
// N=50000, E=1.6M, F_IN=C=64, B=64

__device__ __forceinline__ float lrelu(float x){ return x > 0.f ? x : 0.2f*x; }
__device__ __forceinline__ float gelu_tanh(float x){
  const float k0 = 0.7978845608028654f; // sqrt(2/pi)
  const float k1 = 0.044715f;
  float t = tanhf(k0 * fmaf(k1*x*x, x, x));
  return 0.5f*x*(1.f + t);
}
__device__ __forceinline__ unsigned short f2bf(float f){
  unsigned int u = __float_as_uint(f);
  u = (u + 0x7fffu + ((u >> 16) & 1u)) >> 16;   // RNE
  return (unsigned short)u;
}
__device__ __forceinline__ float bf2f(unsigned short u){
  return __uint_as_float((unsigned int)u << 16);
}
__device__ __forceinline__ float bflo(unsigned int u){ return __uint_as_float(u << 16); }
__device__ __forceinline__ float bfhi(unsigned int u){ return __uint_as_float(u & 0xffff0000u); }
__device__ __forceinline__ unsigned int packbf(float a, float b){
  return ((unsigned int)f2bf(b) << 16) | (unsigned int)f2bf(a);
}
// fp8 e4m3 (OCP) via gfx950 HW converts
__device__ __forceinline__ unsigned char f2fp8(float v){
  return (unsigned char)(__builtin_amdgcn_cvt_pk_fp8_f32(v, v, 0, false) & 0xff);
}
typedef __attribute__((ext_vector_type(2))) float f32x2;

typedef __attribute__((ext_vector_type(8))) short bf16x8;
typedef __attribute__((ext_vector_type(4))) float f32x4;

// ---- zero the accumulator zone ----
__global__ void k_zero(float* __restrict__ p, int n){
  int i = blockIdx.x*blockDim.x + threadIdx.x;
  if (i < n) p[i] = 0.f;
}

// ================= CSR build via 2-level bucket sort =================
// R17 post-mortem: p_bin was pinned at 44us by per-bucket global atomic claim
// chains (782 blocks x 512 buckets -> ~780 serialized atomics/address ~ 20us)
// plus 5x scattered-write line amp. Fix: persistent 256 blocks (1/CU), each
// owning a contiguous E/256 slice -> 256-deep chains (~6us) and ~48B runs.
__global__ void p_hist(const int* __restrict__ dst, int* __restrict__ bhist,
                       int E, int NB){
  __shared__ int lh[512];
  for (int i = threadIdx.x; i < NB; i += blockDim.x) lh[i] = 0;
  __syncthreads();
  int stride = gridDim.x * blockDim.x;
  for (int i = blockIdx.x*blockDim.x + threadIdx.x; i < E; i += stride)
    atomicAdd(&lh[dst[i] >> 7], 1);
  __syncthreads();
  for (int i = threadIdx.x; i < NB; i += blockDim.x)
    if (lh[i]) atomicAdd(&bhist[i], lh[i]);
}

__global__ void p_scan(const int* __restrict__ bhist, int* __restrict__ boff,
                       int* __restrict__ bcur, int* __restrict__ ptr,
                       int NB, int N, int E){
  __shared__ int ls[512];
  int t = threadIdx.x;
  int v = (t < NB) ? bhist[t] : 0;
  ls[t] = v; __syncthreads();
  for (int o = 1; o < 512; o <<= 1){
    int y = (t >= o) ? ls[t-o] : 0;
    __syncthreads();
    ls[t] += y;
    __syncthreads();
  }
  int ex = ls[t] - v;
  if (t < NB){ boff[t] = ex; bcur[t] = ex; }
  if (t == 0){ boff[NB] = E; ptr[N] = E; }
}

#define PBIN_BLOCKS 256
__global__ void p_bin(const int* __restrict__ src, const int* __restrict__ dst,
                      int* __restrict__ bcur, unsigned int* __restrict__ recs,
                      int E, int NB){
  __shared__ int lh[512];
  __shared__ int lbase[512];
  int per = (E + PBIN_BLOCKS - 1) / PBIN_BLOCKS;
  int c0 = blockIdx.x * per;
  int cnt = min(per, E - c0);
  if (cnt <= 0) return;
  int t = threadIdx.x;
  for (int i = t; i < NB; i += blockDim.x) lh[i] = 0;
  __syncthreads();
  for (int i = t; i < cnt; i += blockDim.x)
    atomicAdd(&lh[dst[c0+i] >> 7], 1);
  __syncthreads();
  for (int i = t; i < NB; i += blockDim.x){
    int c = lh[i];
    lbase[i] = (c > 0) ? atomicAdd(&bcur[i], c) : 0;
    lh[i] = 0;
  }
  __syncthreads();
  for (int i = t; i < cnt; i += blockDim.x){
    int d = dst[c0+i];
    int b = d >> 7;
    int p = atomicAdd(&lh[b], 1);
    recs[lbase[b] + p] = ((unsigned int)src[c0+i] << 7) | (unsigned int)(d & 127);
  }
}

__global__ void p_csr(const unsigned int* __restrict__ recs, const int* __restrict__ boff,
                      int* __restrict__ ptr, int* __restrict__ srcs, int N){
  int b = blockIdx.x;
  int r0 = boff[b], r1 = boff[b+1];
  __shared__ int lh[128];
  int t = threadIdx.x;
  if (t < 128) lh[t] = 0;
  __syncthreads();
  for (int i = r0 + t; i < r1; i += 256)
    atomicAdd(&lh[recs[i] & 127u], 1);
  __syncthreads();
  int mycnt = (t < 128) ? lh[t] : 0;
  for (int o = 1; o < 128; o <<= 1){
    int y = (t < 128 && t >= o) ? lh[t-o] : 0;
    __syncthreads();
    if (t < 128) lh[t] += y;
    __syncthreads();
  }
  if (t < 128){
    int excl = lh[t] - mycnt;
    int node = b*128 + t;
    if (node < N) ptr[node] = r0 + excl;
    lh[t] = excl;
  }
  __syncthreads();
  for (int i = r0 + t; i < r1; i += 256){
    unsigned int rec = recs[i];
    int j = rec & 127u;
    int p = atomicAdd(&lh[j], 1);
    srcs[r0 + p] = (int)(rec >> 7);
  }
}

// ---- MFMA GEMM layer 1: [W1 h0 | W1 h1 | skipW]. H stored fp8 e4m3
// (gather-only buffer; softmax weights & dots stay fp32). skv bf16.
__global__ void k_gemm3(const float* __restrict__ X, const float* __restrict__ Wm,
                        const float* __restrict__ Wsk, const float* __restrict__ att_s,
                        const float* __restrict__ att_d, unsigned char* __restrict__ Hout,
                        unsigned short* __restrict__ skv, float* __restrict__ a_s,
                        float* __restrict__ a_d, int N){
  constexpr int NT = 12;
  __shared__ unsigned short Bl[NT*2*64*8];
  int t = threadIdx.x;
  const int TOT = 64 * 192;
  for (int e = t; e < TOT; e += 256){
    int k = e / 192, c = e % 192;
    float w = (c < 128) ? Wm[(size_t)k*128 + c] : Wsk[(size_t)k*64 + (c-128)];
    int ct = c >> 4;
    int h = k >> 5, kk = k & 31;
    int e2 = ((kk >> 4) << 2) | (kk & 3);
    int l  = (c & 15) | (((kk >> 2) & 3) << 4);
    Bl[(((ct*2 + h)*64) + l)*8 + e2] = f2bf(w);
  }
  __syncthreads();

  int lane = t & 63, wav = t >> 6;
  int m = lane & 15, g = lane >> 4;
  float asv[8], adv[8];
  #pragma unroll
  for (int ct = 0; ct < 8; ct++){ asv[ct] = att_s[ct*16 + m]; adv[ct] = att_d[ct*16 + m]; }

  #pragma unroll
  for (int it = 0; it < 2; it++){
    int rbase = blockIdx.x*128 + it*64 + wav*16;
    if (rbase >= N) break;
    int r = min(rbase + m, N-1);
    const float* xr = X + (size_t)r*64;
    float4 u0 = *(const float4*)(xr + g*4);
    float4 u1 = *(const float4*)(xr + 16 + g*4);
    float4 u2 = *(const float4*)(xr + 32 + g*4);
    float4 u3 = *(const float4*)(xr + 48 + g*4);
    bf16x8 a0, a1;
    a0[0]=(short)f2bf(u0.x); a0[1]=(short)f2bf(u0.y); a0[2]=(short)f2bf(u0.z); a0[3]=(short)f2bf(u0.w);
    a0[4]=(short)f2bf(u1.x); a0[5]=(short)f2bf(u1.y); a0[6]=(short)f2bf(u1.z); a0[7]=(short)f2bf(u1.w);
    a1[0]=(short)f2bf(u2.x); a1[1]=(short)f2bf(u2.y); a1[2]=(short)f2bf(u2.z); a1[3]=(short)f2bf(u2.w);
    a1[4]=(short)f2bf(u3.x); a1[5]=(short)f2bf(u3.y); a1[6]=(short)f2bf(u3.z); a1[7]=(short)f2bf(u3.w);

    f32x4 acc[NT];
    #pragma unroll
    for (int ct = 0; ct < NT; ct++) acc[ct] = (f32x4){0.f,0.f,0.f,0.f};
    #pragma unroll
    for (int ct = 0; ct < NT; ct++){
      bf16x8 b0 = *(const bf16x8*)&Bl[((ct*2+0)*64 + lane)*8];
      bf16x8 b1 = *(const bf16x8*)&Bl[((ct*2+1)*64 + lane)*8];
      acc[ct] = __builtin_amdgcn_mfma_f32_16x16x32_bf16(a0, b0, acc[ct], 0, 0, 0);
      acc[ct] = __builtin_amdgcn_mfma_f32_16x16x32_bf16(a1, b1, acc[ct], 0, 0, 0);
    }

    float ds0[4]={0,0,0,0}, dd0[4]={0,0,0,0}, ds1[4]={0,0,0,0}, dd1[4]={0,0,0,0};
    #pragma unroll
    for (int ct = 0; ct < 8; ct++){
      #pragma unroll
      for (int q = 0; q < 4; q++){
        float v = acc[ct][q];
        if (ct < 4){ ds0[q] = fmaf(v, asv[ct], ds0[q]); dd0[q] = fmaf(v, adv[ct], dd0[q]); }
        else       { ds1[q] = fmaf(v, asv[ct], ds1[q]); dd1[q] = fmaf(v, adv[ct], dd1[q]); }
      }
    }
    #pragma unroll
    for (int off = 1; off < 16; off <<= 1){
      #pragma unroll
      for (int q = 0; q < 4; q++){
        ds0[q] += __shfl_xor(ds0[q], off); dd0[q] += __shfl_xor(dd0[q], off);
        ds1[q] += __shfl_xor(ds1[q], off); dd1[q] += __shfl_xor(dd1[q], off);
      }
    }
    if (m == 0){
      #pragma unroll
      for (int q = 0; q < 4; q++){
        int rr = rbase + g*4 + q;
        if (rr < N){
          float2 s2; s2.x = ds0[q]; s2.y = ds1[q]; ((float2*)a_s)[rr] = s2;
          float2 d2; d2.x = dd0[q]; d2.y = dd1[q]; ((float2*)a_d)[rr] = d2;
        }
      }
    }
    #pragma unroll
    for (int ct = 0; ct < 8; ct++){
      #pragma unroll
      for (int q = 0; q < 4; q++){
        int rr = rbase + g*4 + q;
        if (rr < N) Hout[(size_t)rr*128 + ct*16 + m] = f2fp8(acc[ct][q]);
      }
    }
    #pragma unroll
    for (int ct = 8; ct < NT; ct++){
      #pragma unroll
      for (int q = 0; q < 4; q++){
        int rr = rbase + g*4 + q;
        if (rr < N) skv[(size_t)rr*64 + (ct-8)*16 + m] = f2bf(acc[ct][q]);
      }
    }
  }
}

// ---- Layer-2 GEMM fused with bn1+skip+gelu (gout/skv bf16 in, hmid bf16 out,
// H out fp8) ----
__global__ void k_gemm2f(const unsigned short* __restrict__ gout, const unsigned short* __restrict__ skv,
                         const float* __restrict__ part, const float* __restrict__ gamma,
                         const float* __restrict__ beta, const float* __restrict__ skb,
                         const float* __restrict__ W2, const float* __restrict__ att_s,
                         const float* __restrict__ att_d,
                         unsigned char* __restrict__ Hout, unsigned short* __restrict__ hmid,
                         float* __restrict__ a_s, float* __restrict__ a_d,
                         int N, float invN){
  constexpr int NT = 8;
  __shared__ unsigned short Bl[NT*2*64*8];
  __shared__ float scs[64], shs[64];
  int t = threadIdx.x;
  if (t < 64){
    float mu  = part[t] * invN;
    float var = fmaxf(part[64+t] * invN - mu*mu, 0.f);
    float sc  = gamma[t] * rsqrtf(var + 1e-5f);
    scs[t] = sc;
    shs[t] = beta[t] - mu*sc + skb[t];
  }
  const int TOT = 64 * 128;
  for (int e = t; e < TOT; e += 256){
    int k = e >> 7, c = e & 127;
    float w = W2[(size_t)k*128 + c];
    int ct = c >> 4;
    int h = k >> 5, kk = k & 31;
    int e2 = ((kk >> 4) << 2) | (kk & 3);
    int l  = (c & 15) | (((kk >> 2) & 3) << 4);
    Bl[(((ct*2 + h)*64) + l)*8 + e2] = f2bf(w);
  }
  __syncthreads();

  int lane = t & 63, wav = t >> 6;
  int m = lane & 15, g = lane >> 4;
  float asv[8], adv[8];
  #pragma unroll
  for (int ct = 0; ct < 8; ct++){ asv[ct] = att_s[ct*16 + m]; adv[ct] = att_d[ct*16 + m]; }

  #pragma unroll
  for (int it = 0; it < 2; it++){
    int rbase = blockIdx.x*128 + it*64 + wav*16;
    if (rbase >= N) break;
    int rm = rbase + m;
    int r = min(rm, N-1);
    const unsigned short* gr = gout + (size_t)r*64;
    const unsigned short* sr = skv + (size_t)r*64;
    float hv[16];
    #pragma unroll
    for (int j = 0; j < 4; j++){
      int c0 = j*16 + g*4;
      uint2 gp = *(const uint2*)(gr + c0);
      uint2 sp = *(const uint2*)(sr + c0);
      float4 sc4 = *(const float4*)(&scs[c0]);
      float4 sh4 = *(const float4*)(&shs[c0]);
      float v0 = gelu_tanh(fmaf(bflo(gp.x), sc4.x, sh4.x) + bflo(sp.x));
      float v1 = gelu_tanh(fmaf(bfhi(gp.x), sc4.y, sh4.y) + bfhi(sp.x));
      float v2 = gelu_tanh(fmaf(bflo(gp.y), sc4.z, sh4.z) + bflo(sp.y));
      float v3 = gelu_tanh(fmaf(bfhi(gp.y), sc4.w, sh4.w) + bfhi(sp.y));
      hv[4*j+0] = v0; hv[4*j+1] = v1; hv[4*j+2] = v2; hv[4*j+3] = v3;
      if (rm < N){
        uint2 hp; hp.x = packbf(v0, v1); hp.y = packbf(v2, v3);
        *(uint2*)(hmid + (size_t)rm*64 + c0) = hp;
      }
    }
    bf16x8 a0, a1;
    #pragma unroll
    for (int i2 = 0; i2 < 8; i2++) a0[i2] = (short)f2bf(hv[i2]);
    #pragma unroll
    for (int i2 = 0; i2 < 8; i2++) a1[i2] = (short)f2bf(hv[8+i2]);

    f32x4 acc[NT];
    #pragma unroll
    for (int ct = 0; ct < NT; ct++) acc[ct] = (f32x4){0.f,0.f,0.f,0.f};
    #pragma unroll
    for (int ct = 0; ct < NT; ct++){
      bf16x8 b0 = *(const bf16x8*)&Bl[((ct*2+0)*64 + lane)*8];
      bf16x8 b1 = *(const bf16x8*)&Bl[((ct*2+1)*64 + lane)*8];
      acc[ct] = __builtin_amdgcn_mfma_f32_16x16x32_bf16(a0, b0, acc[ct], 0, 0, 0);
      acc[ct] = __builtin_amdgcn_mfma_f32_16x16x32_bf16(a1, b1, acc[ct], 0, 0, 0);
    }

    float ds0[4]={0,0,0,0}, dd0[4]={0,0,0,0}, ds1[4]={0,0,0,0}, dd1[4]={0,0,0,0};
    #pragma unroll
    for (int ct = 0; ct < 8; ct++){
      #pragma unroll
      for (int q = 0; q < 4; q++){
        float v = acc[ct][q];
        if (ct < 4){ ds0[q] = fmaf(v, asv[ct], ds0[q]); dd0[q] = fmaf(v, adv[ct], dd0[q]); }
        else       { ds1[q] = fmaf(v, asv[ct], ds1[q]); dd1[q] = fmaf(v, adv[ct], dd1[q]); }
      }
    }
    #pragma unroll
    for (int off = 1; off < 16; off <<= 1){
      #pragma unroll
      for (int q = 0; q < 4; q++){
        ds0[q] += __shfl_xor(ds0[q], off); dd0[q] += __shfl_xor(dd0[q], off);
        ds1[q] += __shfl_xor(ds1[q], off); dd1[q] += __shfl_xor(dd1[q], off);
      }
    }
    if (m == 0){
      #pragma unroll
      for (int q = 0; q < 4; q++){
        int rr = rbase + g*4 + q;
        if (rr < N){
          float2 s2; s2.x = ds0[q]; s2.y = ds1[q]; ((float2*)a_s)[rr] = s2;
          float2 d2; d2.x = dd0[q]; d2.y = dd1[q]; ((float2*)a_d)[rr] = d2;
        }
      }
    }
    #pragma unroll
    for (int ct = 0; ct < 8; ct++){
      #pragma unroll
      for (int q = 0; q < 4; q++){
        int rr = rbase + g*4 + q;
        if (rr < N) Hout[(size_t)rr*128 + ct*16 + m] = f2fp8(acc[ct][q]);
      }
    }
  }
}

// ---- GAT aggregation v2: half-wave per edge (2 edges/iter). Each lane covers
// 4 flat channels (dword fp8 load + 2x cvt_pk unpack); weight via 4-addr LDS
// broadcast; parity-sum shfl(32), per-head normalize, head-mean shfl(16).
// (R13 lesson kept: NO fused BN stats.)
__global__ void k_agg(const unsigned char* __restrict__ Hp, const float* __restrict__ a_s,
                      const float* __restrict__ a_d, const int* __restrict__ ptr,
                      const int* __restrict__ srcs, const float* __restrict__ bias,
                      unsigned int* __restrict__ out, int N){
  __shared__ unsigned int sbuf[4][64];
  __shared__ float wbuf[4][2][64];
  int tid = threadIdx.x;
  int wv = tid >> 6;
  int wid = (blockIdx.x*blockDim.x + tid) >> 6;
  int lane = tid & 63;
  if (wid >= N) return;
  int n = wid;
  const char* HB = (const char*)Hp;            // rows of 128 B
  const float2* AS2 = (const float2*)a_s;
  float2 adv = ((const float2*)a_d)[n];
  float2 asv = AS2[n];
  int e0 = ptr[n], e1 = ptr[n+1];
  float w0 = __expf(lrelu(asv.x + adv.x));
  float w1 = __expf(lrelu(asv.y + adv.y));
  int half = lane >> 5;          // edge parity within pair
  int q    = lane & 31;          // channel group: flat channels 4q..4q+3
  int hsel = q >> 4;             // head of my channels
  unsigned qb = (unsigned)q << 2;
  // self row (counted once: only parity 0 accumulates)
  unsigned int hw = *(const unsigned int*)(HB + (((unsigned)n << 7) | qb));
  f32x2 s01 = __builtin_amdgcn_cvt_pk_f32_fp8((int)hw, false);
  f32x2 s23 = __builtin_amdgcn_cvt_pk_f32_fp8((int)hw, true);
  float wself = (half == 0) ? ((hsel == 0) ? w0 : w1) : 0.f;
  float acc0 = s01.x * wself, acc1 = s01.y * wself;
  float acc2 = s23.x * wself, acc3 = s23.y * wself;
  float d0 = 0.f, d1 = 0.f;
  for (int base = e0; base < e1; base += 64){
    int i = base + lane;
    float e_0 = 0.f, e_1 = 0.f; unsigned sv = 0;
    if (i < e1){
      sv = (unsigned)srcs[i];
      float2 av = AS2[sv];
      e_0 = __expf(lrelu(av.x + adv.x));
      e_1 = __expf(lrelu(av.y + adv.y));
    }
    d0 += e_0; d1 += e_1;
    sbuf[wv][lane] = sv << 7;                 // row byte offset (128 B rows)
    wbuf[wv][0][lane] = e_0;
    wbuf[wv][1][lane] = e_1;
    int cnt = min(64, e1 - base);
    #pragma unroll 8
    for (int j = 0; j < cnt; j += 2){
      int jj = j + half;                      // odd tail: slot cnt has 0-weight
      unsigned off = sbuf[wv][jj];
      float wss = wbuf[wv][hsel][jj];
      unsigned int hj = *(const unsigned int*)(HB + (off | qb));
      f32x2 h01 = __builtin_amdgcn_cvt_pk_f32_fp8((int)hj, false);
      f32x2 h23 = __builtin_amdgcn_cvt_pk_f32_fp8((int)hj, true);
      acc0 = fmaf(h01.x, wss, acc0);
      acc1 = fmaf(h01.y, wss, acc1);
      acc2 = fmaf(h23.x, wss, acc2);
      acc3 = fmaf(h23.y, wss, acc3);
    }
  }
  #pragma unroll
  for (int o=32;o>0;o>>=1){ d0 += __shfl_xor(d0,o); d1 += __shfl_xor(d1,o); }
  d0 += w0; d1 += w1;
  // parity sum (edge halves)
  acc0 += __shfl_xor(acc0, 32);
  acc1 += __shfl_xor(acc1, 32);
  acc2 += __shfl_xor(acc2, 32);
  acc3 += __shfl_xor(acc3, 32);
  float dsel = (hsel == 0) ? d0 : d1;
  acc0 /= dsel; acc1 /= dsel; acc2 /= dsel; acc3 /= dsel;
  // head mean: q (head0 chans 4q..) pairs with q+16 (head1 same chans)
  float m0 = 0.5f*(acc0 + __shfl_xor(acc0, 16));
  float m1 = 0.5f*(acc1 + __shfl_xor(acc1, 16));
  float m2 = 0.5f*(acc2 + __shfl_xor(acc2, 16));
  float m3 = 0.5f*(acc3 + __shfl_xor(acc3, 16));
  if (half == 0 && q < 16){
    float4 b4 = *(const float4*)(bias + 4*q);
    uint2 res;
    res.x = packbf(m0 + b4.x, m1 + b4.y);
    res.y = packbf(m2 + b4.z, m3 + b4.w);
    *(uint2*)(out + (size_t)n*32 + 2*q) = res;
  }
}

// ---- BN stats: per-channel sum / sumsq over bf16 input (256 blocks) ----
__global__ void k_bnstats(const unsigned short* __restrict__ X, float* __restrict__ part, int N){
  int t = threadIdx.x; int c = t & 63; int sub = t >> 6;
  float s = 0.f, s2 = 0.f;
  for (int r = blockIdx.x*4 + sub; r < N; r += gridDim.x*4){
    float v = bf2f(X[(size_t)r*64 + c]);
    s += v; s2 = fmaf(v, v, s2);
  }
  __shared__ float ls[256], lq[256];
  ls[t] = s; lq[t] = s2; __syncthreads();
  if (t < 64){
    s  = ls[t] + ls[t+64] + ls[t+128] + ls[t+192];
    s2 = lq[t] + lq[t+64] + lq[t+128] + lq[t+192];
    atomicAdd(&part[t], s);
    atomicAdd(&part[64+t], s2);
  }
}

// ---- final: gelu(bn(g2)+hmid), pooled sums per batch; bn derived inline ----
__global__ void k_fusepool(const unsigned short* __restrict__ g2, const float* __restrict__ part,
                           const float* __restrict__ gamma, const float* __restrict__ beta,
                           const unsigned short* __restrict__ hmid, const int* __restrict__ batch,
                           float* __restrict__ pool, float* __restrict__ cnt, int N, float invN){
  int t = threadIdx.x; int c = t & 63; int sub = t >> 6;
  int r0 = blockIdx.x*64;
  float mu  = part[c] * invN;
  float var = fmaxf(part[64+c] * invN - mu*mu, 0.f);
  float scale = gamma[c] * rsqrtf(var + 1e-5f);
  float shift = beta[c] - mu*scale;
  float acc = 0.f, ca = 0.f; int curb = -1;
  for (int r = r0 + sub; r < N && r < r0 + 64; r += 4){
    int b = batch[r];
    if (b != curb){
      if (curb >= 0){
        atomicAdd(&pool[curb*64 + c], acc);
        if (c == 0) atomicAdd(&cnt[curb], ca);
      }
      acc = 0.f; ca = 0.f; curb = b;
    }
    float gv = bf2f(g2[(size_t)r*64 + c]);
    float hv = bf2f(hmid[(size_t)r*64 + c]);
    float v = gelu_tanh(fmaf(gv, scale, shift) + hv);
    acc += v; ca += 1.f;
  }
  if (curb >= 0){
    atomicAdd(&pool[curb*64 + c], acc);
    if (c == 0) atomicAdd(&cnt[curb], ca);
  }
}

__global__ void k_out(const float* __restrict__ pool, const float* __restrict__ cnt,
                      float* __restrict__ out, int M){
  int i = blockIdx.x*blockDim.x + threadIdx.x;
  if (i < M) out[i] = pool[i] / fmaxf(cnt[i>>6], 1.f);
}

extern "C" void kernel_launch(void* const* d_in, const int* in_sizes, int n_in,
                              void* d_out, int out_size, void* d_ws, size_t ws_size,
                              hipStream_t stream) {
  const float* x     = (const float*)d_in[0];
  const int*   ei    = (const int*)  d_in[1];
  const int*   batch = (const int*)  d_in[2];
  const float* W1    = (const float*)d_in[3];
  const float* as1   = (const float*)d_in[4];
  const float* ad1   = (const float*)d_in[5];
  const float* b1    = (const float*)d_in[6];
  const float* skW   = (const float*)d_in[7];
  const float* skb   = (const float*)d_in[8];
  const float* gm1   = (const float*)d_in[9];
  const float* bt1   = (const float*)d_in[10];
  const float* W2    = (const float*)d_in[11];
  const float* as2   = (const float*)d_in[12];
  const float* ad2   = (const float*)d_in[13];
  const float* b2    = (const float*)d_in[14];
  const float* gm2   = (const float*)d_in[15];
  const float* bt2   = (const float*)d_in[16];

  int N = in_sizes[2];
  int E = in_sizes[1] / 2;
  const int* esrc = ei;
  const int* edst = ei + E;
  int NB = (N + 127) >> 7;          // 128-node buckets
  float invN = 1.0f / (float)N;

  char* wp = (char*)d_ws;
  size_t off = 0;
  auto alloc = [&](size_t bytes)->void*{
    off = (off + 255) & ~(size_t)255;
    void* p = wp + off;
    off += bytes;
    return p;
  };
  int*   ptr   = (int*)  alloc((size_t)(N+1)*4);
  int*   srcs  = (int*)  alloc((size_t)E*4);
  unsigned int* recs = (unsigned int*)alloc((size_t)E*4);
  int*   boff  = (int*)  alloc(520*4);
  int*   bcur  = (int*)  alloc(512*4);
  unsigned char* hpack = (unsigned char*)alloc((size_t)N*128);    // fp8 H
  float* a_s  = (float*)alloc((size_t)N*2*4);
  float* a_d  = (float*)alloc((size_t)N*2*4);
  unsigned short* gout = (unsigned short*)alloc((size_t)N*64*2);  // bf16 GAT out
  unsigned short* skv  = (unsigned short*)alloc((size_t)N*64*2);  // bf16 x@skipW
  unsigned short* hmid = (unsigned short*)alloc((size_t)N*64*2);  // bf16 layer-1 out
  // zero zone: part1[128] part2[128] pool[4096] cnt[64] bhist[512]
  const int ZN = 128+128+4096+64+512;
  float* zz   = (float*)alloc((size_t)ZN*4);
  float* part1 = zz;
  float* part2 = zz + 128;
  float* pool  = zz + 256;
  float* cnt   = zz + 256 + 4096;
  int*   bhist = (int*)(zz + 256 + 4096 + 64);

  int gg = (N + 127) / 128;

  // zero accumulators
  k_zero<<<(ZN + 255)/256, 256, 0, stream>>>(zz, ZN);

  // CSR build (bucket sort; persistent p_bin to avoid atomic claim chains)
  p_hist<<<256, 256, 0, stream>>>(edst, bhist, E, NB);
  p_scan<<<1, 512, 0, stream>>>(bhist, boff, bcur, ptr, NB, N, E);
  p_bin<<<PBIN_BLOCKS, 512, 0, stream>>>(esrc, edst, bcur, recs, E, NB);
  p_csr<<<NB, 256, 0, stream>>>(recs, boff, ptr, srcs, N);

  // layer 1 (W1 + skip + att fused, MFMA)
  k_gemm3<<<gg, 256, 0, stream>>>(x, W1, skW, as1, ad1, hpack, skv, a_s, a_d, N);
  k_agg<<<(N+3)/4, 256, 0, stream>>>(hpack, a_s, a_d, ptr, srcs, b1, (unsigned int*)gout, N);
  k_bnstats<<<256, 256, 0, stream>>>(gout, part1, N);

  // layer 2: GEMM fused with bn1+skip+gelu (writes hmid)
  k_gemm2f<<<gg, 256, 0, stream>>>(gout, skv, part1, gm1, bt1, skb, W2, as2, ad2,
                                   hpack, hmid, a_s, a_d, N, invN);
  k_agg<<<(N+3)/4, 256, 0, stream>>>(hpack, a_s, a_d, ptr, srcs, b2, (unsigned int*)gout, N);
  k_bnstats<<<256, 256, 0, stream>>>(gout, part2, N);

  // fuse + pool (bn2 derived inline)
  k_fusepool<<<(N+63)/64, 256, 0, stream>>>(gout, part2, gm2, bt2, hmid, batch, pool, cnt, N, invN);
  k_out<<<(out_size + 255)/256, 256, 0, stream>>>(pool, cnt, (float*)d_out, out_size);
}

// Round 19
// 242.056 us; speedup vs baseline: 1.0920x; 1.0920x over previous
//
#include <hip/hip_runtime.h>
#include <math.h>

// GraphBlock: 2x GATConv(H=2 heads, C=64, concat=False) + BN(train) + GELU + skip + mean-pool
// N=50000, E=1.6M, F_IN=C=64, B=64

__device__ __forceinline__ float lrelu(float x){ return x > 0.f ? x : 0.2f*x; }
__device__ __forceinline__ float gelu_tanh(float x){
  const float k0 = 0.7978845608028654f; // sqrt(2/pi)
  const float k1 = 0.044715f;
  float t = tanhf(k0 * fmaf(k1*x*x, x, x));
  return 0.5f*x*(1.f + t);
}
__device__ __forceinline__ unsigned short f2bf(float f){
  unsigned int u = __float_as_uint(f);
  u = (u + 0x7fffu + ((u >> 16) & 1u)) >> 16;   // RNE
  return (unsigned short)u;
}
__device__ __forceinline__ float bf2f(unsigned short u){
  return __uint_as_float((unsigned int)u << 16);
}
__device__ __forceinline__ float bflo(unsigned int u){ return __uint_as_float(u << 16); }
__device__ __forceinline__ float bfhi(unsigned int u){ return __uint_as_float(u & 0xffff0000u); }
__device__ __forceinline__ unsigned int packbf(float a, float b){
  return ((unsigned int)f2bf(b) << 16) | (unsigned int)f2bf(a);
}
// fp8 e4m3 (OCP) via gfx950 HW converts
__device__ __forceinline__ unsigned char f2fp8(float v){
  return (unsigned char)(__builtin_amdgcn_cvt_pk_fp8_f32(v, v, 0, false) & 0xff);
}
typedef __attribute__((ext_vector_type(2))) float f32x2;

typedef __attribute__((ext_vector_type(8))) short bf16x8;
typedef __attribute__((ext_vector_type(4))) float f32x4;

// ---- zero the accumulator zone ----
__global__ void k_zero(float* __restrict__ p, int n){
  int i = blockIdx.x*blockDim.x + threadIdx.x;
  if (i < n) p[i] = 0.f;
}

// ================= CSR build via 2-level bucket sort =================
// Persistent p_bin (256 blocks, 1/CU) avoids per-bucket global atomic claim
// chains (R17: 44us pinned) — confirmed off the top-5 in R18.
__global__ void p_hist(const int* __restrict__ dst, int* __restrict__ bhist,
                       int E, int NB){
  __shared__ int lh[512];
  for (int i = threadIdx.x; i < NB; i += blockDim.x) lh[i] = 0;
  __syncthreads();
  int stride = gridDim.x * blockDim.x;
  for (int i = blockIdx.x*blockDim.x + threadIdx.x; i < E; i += stride)
    atomicAdd(&lh[dst[i] >> 7], 1);
  __syncthreads();
  for (int i = threadIdx.x; i < NB; i += blockDim.x)
    if (lh[i]) atomicAdd(&bhist[i], lh[i]);
}

__global__ void p_scan(const int* __restrict__ bhist, int* __restrict__ boff,
                       int* __restrict__ bcur, int* __restrict__ ptr,
                       int NB, int N, int E){
  __shared__ int ls[512];
  int t = threadIdx.x;
  int v = (t < NB) ? bhist[t] : 0;
  ls[t] = v; __syncthreads();
  for (int o = 1; o < 512; o <<= 1){
    int y = (t >= o) ? ls[t-o] : 0;
    __syncthreads();
    ls[t] += y;
    __syncthreads();
  }
  int ex = ls[t] - v;
  if (t < NB){ boff[t] = ex; bcur[t] = ex; }
  if (t == 0){ boff[NB] = E; ptr[N] = E; }
}

#define PBIN_BLOCKS 256
__global__ void p_bin(const int* __restrict__ src, const int* __restrict__ dst,
                      int* __restrict__ bcur, unsigned int* __restrict__ recs,
                      int E, int NB){
  __shared__ int lh[512];
  __shared__ int lbase[512];
  int per = (E + PBIN_BLOCKS - 1) / PBIN_BLOCKS;
  int c0 = blockIdx.x * per;
  int cnt = min(per, E - c0);
  if (cnt <= 0) return;
  int t = threadIdx.x;
  for (int i = t; i < NB; i += blockDim.x) lh[i] = 0;
  __syncthreads();
  for (int i = t; i < cnt; i += blockDim.x)
    atomicAdd(&lh[dst[c0+i] >> 7], 1);
  __syncthreads();
  for (int i = t; i < NB; i += blockDim.x){
    int c = lh[i];
    lbase[i] = (c > 0) ? atomicAdd(&bcur[i], c) : 0;
    lh[i] = 0;
  }
  __syncthreads();
  for (int i = t; i < cnt; i += blockDim.x){
    int d = dst[c0+i];
    int b = d >> 7;
    int p = atomicAdd(&lh[b], 1);
    recs[lbase[b] + p] = ((unsigned int)src[c0+i] << 7) | (unsigned int)(d & 127);
  }
}

__global__ void p_csr(const unsigned int* __restrict__ recs, const int* __restrict__ boff,
                      int* __restrict__ ptr, int* __restrict__ srcs, int N){
  int b = blockIdx.x;
  int r0 = boff[b], r1 = boff[b+1];
  __shared__ int lh[128];
  int t = threadIdx.x;
  if (t < 128) lh[t] = 0;
  __syncthreads();
  for (int i = r0 + t; i < r1; i += 256)
    atomicAdd(&lh[recs[i] & 127u], 1);
  __syncthreads();
  int mycnt = (t < 128) ? lh[t] : 0;
  for (int o = 1; o < 128; o <<= 1){
    int y = (t < 128 && t >= o) ? lh[t-o] : 0;
    __syncthreads();
    if (t < 128) lh[t] += y;
    __syncthreads();
  }
  if (t < 128){
    int excl = lh[t] - mycnt;
    int node = b*128 + t;
    if (node < N) ptr[node] = r0 + excl;
    lh[t] = excl;
  }
  __syncthreads();
  for (int i = r0 + t; i < r1; i += 256){
    unsigned int rec = recs[i];
    int j = rec & 127u;
    int p = atomicAdd(&lh[j], 1);
    srcs[r0 + p] = (int)(rec >> 7);
  }
}

// ---- MFMA GEMM layer 1: [W1 h0 | W1 h1 | skipW]. H stored fp8 e4m3
// (gather-only buffer; softmax weights & dots stay fp32). skv bf16.
__global__ void k_gemm3(const float* __restrict__ X, const float* __restrict__ Wm,
                        const float* __restrict__ Wsk, const float* __restrict__ att_s,
                        const float* __restrict__ att_d, unsigned char* __restrict__ Hout,
                        unsigned short* __restrict__ skv, float* __restrict__ a_s,
                        float* __restrict__ a_d, int N){
  constexpr int NT = 12;
  __shared__ unsigned short Bl[NT*2*64*8];
  int t = threadIdx.x;
  const int TOT = 64 * 192;
  for (int e = t; e < TOT; e += 256){
    int k = e / 192, c = e % 192;
    float w = (c < 128) ? Wm[(size_t)k*128 + c] : Wsk[(size_t)k*64 + (c-128)];
    int ct = c >> 4;
    int h = k >> 5, kk = k & 31;
    int e2 = ((kk >> 4) << 2) | (kk & 3);
    int l  = (c & 15) | (((kk >> 2) & 3) << 4);
    Bl[(((ct*2 + h)*64) + l)*8 + e2] = f2bf(w);
  }
  __syncthreads();

  int lane = t & 63, wav = t >> 6;
  int m = lane & 15, g = lane >> 4;
  float asv[8], adv[8];
  #pragma unroll
  for (int ct = 0; ct < 8; ct++){ asv[ct] = att_s[ct*16 + m]; adv[ct] = att_d[ct*16 + m]; }

  #pragma unroll
  for (int it = 0; it < 2; it++){
    int rbase = blockIdx.x*128 + it*64 + wav*16;
    if (rbase >= N) break;
    int r = min(rbase + m, N-1);
    const float* xr = X + (size_t)r*64;
    float4 u0 = *(const float4*)(xr + g*4);
    float4 u1 = *(const float4*)(xr + 16 + g*4);
    float4 u2 = *(const float4*)(xr + 32 + g*4);
    float4 u3 = *(const float4*)(xr + 48 + g*4);
    bf16x8 a0, a1;
    a0[0]=(short)f2bf(u0.x); a0[1]=(short)f2bf(u0.y); a0[2]=(short)f2bf(u0.z); a0[3]=(short)f2bf(u0.w);
    a0[4]=(short)f2bf(u1.x); a0[5]=(short)f2bf(u1.y); a0[6]=(short)f2bf(u1.z); a0[7]=(short)f2bf(u1.w);
    a1[0]=(short)f2bf(u2.x); a1[1]=(short)f2bf(u2.y); a1[2]=(short)f2bf(u2.z); a1[3]=(short)f2bf(u2.w);
    a1[4]=(short)f2bf(u3.x); a1[5]=(short)f2bf(u3.y); a1[6]=(short)f2bf(u3.z); a1[7]=(short)f2bf(u3.w);

    f32x4 acc[NT];
    #pragma unroll
    for (int ct = 0; ct < NT; ct++) acc[ct] = (f32x4){0.f,0.f,0.f,0.f};
    #pragma unroll
    for (int ct = 0; ct < NT; ct++){
      bf16x8 b0 = *(const bf16x8*)&Bl[((ct*2+0)*64 + lane)*8];
      bf16x8 b1 = *(const bf16x8*)&Bl[((ct*2+1)*64 + lane)*8];
      acc[ct] = __builtin_amdgcn_mfma_f32_16x16x32_bf16(a0, b0, acc[ct], 0, 0, 0);
      acc[ct] = __builtin_amdgcn_mfma_f32_16x16x32_bf16(a1, b1, acc[ct], 0, 0, 0);
    }

    float ds0[4]={0,0,0,0}, dd0[4]={0,0,0,0}, ds1[4]={0,0,0,0}, dd1[4]={0,0,0,0};
    #pragma unroll
    for (int ct = 0; ct < 8; ct++){
      #pragma unroll
      for (int q = 0; q < 4; q++){
        float v = acc[ct][q];
        if (ct < 4){ ds0[q] = fmaf(v, asv[ct], ds0[q]); dd0[q] = fmaf(v, adv[ct], dd0[q]); }
        else       { ds1[q] = fmaf(v, asv[ct], ds1[q]); dd1[q] = fmaf(v, adv[ct], dd1[q]); }
      }
    }
    #pragma unroll
    for (int off = 1; off < 16; off <<= 1){
      #pragma unroll
      for (int q = 0; q < 4; q++){
        ds0[q] += __shfl_xor(ds0[q], off); dd0[q] += __shfl_xor(dd0[q], off);
        ds1[q] += __shfl_xor(ds1[q], off); dd1[q] += __shfl_xor(dd1[q], off);
      }
    }
    if (m == 0){
      #pragma unroll
      for (int q = 0; q < 4; q++){
        int rr = rbase + g*4 + q;
        if (rr < N){
          float2 s2; s2.x = ds0[q]; s2.y = ds1[q]; ((float2*)a_s)[rr] = s2;
          float2 d2; d2.x = dd0[q]; d2.y = dd1[q]; ((float2*)a_d)[rr] = d2;
        }
      }
    }
    #pragma unroll
    for (int ct = 0; ct < 8; ct++){
      #pragma unroll
      for (int q = 0; q < 4; q++){
        int rr = rbase + g*4 + q;
        if (rr < N) Hout[(size_t)rr*128 + ct*16 + m] = f2fp8(acc[ct][q]);
      }
    }
    #pragma unroll
    for (int ct = 8; ct < NT; ct++){
      #pragma unroll
      for (int q = 0; q < 4; q++){
        int rr = rbase + g*4 + q;
        if (rr < N) skv[(size_t)rr*64 + (ct-8)*16 + m] = f2bf(acc[ct][q]);
      }
    }
  }
}

// ---- Layer-2 GEMM fused with bn1+skip+gelu (gout/skv bf16 in, hmid bf16 out,
// H out fp8) ----
__global__ void k_gemm2f(const unsigned short* __restrict__ gout, const unsigned short* __restrict__ skv,
                         const float* __restrict__ part, const float* __restrict__ gamma,
                         const float* __restrict__ beta, const float* __restrict__ skb,
                         const float* __restrict__ W2, const float* __restrict__ att_s,
                         const float* __restrict__ att_d,
                         unsigned char* __restrict__ Hout, unsigned short* __restrict__ hmid,
                         float* __restrict__ a_s, float* __restrict__ a_d,
                         int N, float invN){
  constexpr int NT = 8;
  __shared__ unsigned short Bl[NT*2*64*8];
  __shared__ float scs[64], shs[64];
  int t = threadIdx.x;
  if (t < 64){
    float mu  = part[t] * invN;
    float var = fmaxf(part[64+t] * invN - mu*mu, 0.f);
    float sc  = gamma[t] * rsqrtf(var + 1e-5f);
    scs[t] = sc;
    shs[t] = beta[t] - mu*sc + skb[t];
  }
  const int TOT = 64 * 128;
  for (int e = t; e < TOT; e += 256){
    int k = e >> 7, c = e & 127;
    float w = W2[(size_t)k*128 + c];
    int ct = c >> 4;
    int h = k >> 5, kk = k & 31;
    int e2 = ((kk >> 4) << 2) | (kk & 3);
    int l  = (c & 15) | (((kk >> 2) & 3) << 4);
    Bl[(((ct*2 + h)*64) + l)*8 + e2] = f2bf(w);
  }
  __syncthreads();

  int lane = t & 63, wav = t >> 6;
  int m = lane & 15, g = lane >> 4;
  float asv[8], adv[8];
  #pragma unroll
  for (int ct = 0; ct < 8; ct++){ asv[ct] = att_s[ct*16 + m]; adv[ct] = att_d[ct*16 + m]; }

  #pragma unroll
  for (int it = 0; it < 2; it++){
    int rbase = blockIdx.x*128 + it*64 + wav*16;
    if (rbase >= N) break;
    int rm = rbase + m;
    int r = min(rm, N-1);
    const unsigned short* gr = gout + (size_t)r*64;
    const unsigned short* sr = skv + (size_t)r*64;
    float hv[16];
    #pragma unroll
    for (int j = 0; j < 4; j++){
      int c0 = j*16 + g*4;
      uint2 gp = *(const uint2*)(gr + c0);
      uint2 sp = *(const uint2*)(sr + c0);
      float4 sc4 = *(const float4*)(&scs[c0]);
      float4 sh4 = *(const float4*)(&shs[c0]);
      float v0 = gelu_tanh(fmaf(bflo(gp.x), sc4.x, sh4.x) + bflo(sp.x));
      float v1 = gelu_tanh(fmaf(bfhi(gp.x), sc4.y, sh4.y) + bfhi(sp.x));
      float v2 = gelu_tanh(fmaf(bflo(gp.y), sc4.z, sh4.z) + bflo(sp.y));
      float v3 = gelu_tanh(fmaf(bfhi(gp.y), sc4.w, sh4.w) + bfhi(sp.y));
      hv[4*j+0] = v0; hv[4*j+1] = v1; hv[4*j+2] = v2; hv[4*j+3] = v3;
      if (rm < N){
        uint2 hp; hp.x = packbf(v0, v1); hp.y = packbf(v2, v3);
        *(uint2*)(hmid + (size_t)rm*64 + c0) = hp;
      }
    }
    bf16x8 a0, a1;
    #pragma unroll
    for (int i2 = 0; i2 < 8; i2++) a0[i2] = (short)f2bf(hv[i2]);
    #pragma unroll
    for (int i2 = 0; i2 < 8; i2++) a1[i2] = (short)f2bf(hv[8+i2]);

    f32x4 acc[NT];
    #pragma unroll
    for (int ct = 0; ct < NT; ct++) acc[ct] = (f32x4){0.f,0.f,0.f,0.f};
    #pragma unroll
    for (int ct = 0; ct < NT; ct++){
      bf16x8 b0 = *(const bf16x8*)&Bl[((ct*2+0)*64 + lane)*8];
      bf16x8 b1 = *(const bf16x8*)&Bl[((ct*2+1)*64 + lane)*8];
      acc[ct] = __builtin_amdgcn_mfma_f32_16x16x32_bf16(a0, b0, acc[ct], 0, 0, 0);
      acc[ct] = __builtin_amdgcn_mfma_f32_16x16x32_bf16(a1, b1, acc[ct], 0, 0, 0);
    }

    float ds0[4]={0,0,0,0}, dd0[4]={0,0,0,0}, ds1[4]={0,0,0,0}, dd1[4]={0,0,0,0};
    #pragma unroll
    for (int ct = 0; ct < 8; ct++){
      #pragma unroll
      for (int q = 0; q < 4; q++){
        float v = acc[ct][q];
        if (ct < 4){ ds0[q] = fmaf(v, asv[ct], ds0[q]); dd0[q] = fmaf(v, adv[ct], dd0[q]); }
        else       { ds1[q] = fmaf(v, asv[ct], ds1[q]); dd1[q] = fmaf(v, adv[ct], dd1[q]); }
      }
    }
    #pragma unroll
    for (int off = 1; off < 16; off <<= 1){
      #pragma unroll
      for (int q = 0; q < 4; q++){
        ds0[q] += __shfl_xor(ds0[q], off); dd0[q] += __shfl_xor(dd0[q], off);
        ds1[q] += __shfl_xor(ds1[q], off); dd1[q] += __shfl_xor(dd1[q], off);
      }
    }
    if (m == 0){
      #pragma unroll
      for (int q = 0; q < 4; q++){
        int rr = rbase + g*4 + q;
        if (rr < N){
          float2 s2; s2.x = ds0[q]; s2.y = ds1[q]; ((float2*)a_s)[rr] = s2;
          float2 d2; d2.x = dd0[q]; d2.y = dd1[q]; ((float2*)a_d)[rr] = d2;
        }
      }
    }
    #pragma unroll
    for (int ct = 0; ct < 8; ct++){
      #pragma unroll
      for (int q = 0; q < 4; q++){
        int rr = rbase + g*4 + q;
        if (rr < N) Hout[(size_t)rr*128 + ct*16 + m] = f2fp8(acc[ct][q]);
      }
    }
  }
}

// ---- GAT aggregation (R16 version — fastest measured at 43us: per-lane
// ushort fp8 gather, 28 VGPR, zero bank conflicts. R18's half-wave pair-edge
// variant regressed to 54us via LDS conflicts + VGPR/occupancy loss.) ----
__global__ void k_agg(const unsigned char* __restrict__ Hp, const float* __restrict__ a_s,
                      const float* __restrict__ a_d, const int* __restrict__ ptr,
                      const int* __restrict__ srcs, const float* __restrict__ bias,
                      unsigned int* __restrict__ out, int N){
  __shared__ unsigned int sbuf[4][64];
  __shared__ float wbuf[4][2][64];
  int tid = threadIdx.x;
  int wv = tid >> 6;
  int wid = (blockIdx.x*blockDim.x + tid) >> 6;
  int lane = tid & 63;
  if (wid >= N) return;
  int n = wid;
  const char* HB = (const char*)Hp;            // rows of 128 B
  const float2* AS2 = (const float2*)a_s;
  float2 adv = ((const float2*)a_d)[n];
  float2 asv = AS2[n];
  int e0 = ptr[n], e1 = ptr[n+1];
  float w0 = __expf(lrelu(asv.x + adv.x));
  float w1 = __expf(lrelu(asv.y + adv.y));
  unsigned lane2 = (unsigned)lane << 1;
  unsigned int hw = *(const unsigned short*)(HB + (((unsigned)n << 7) | lane2));
  f32x2 hv = __builtin_amdgcn_cvt_pk_f32_fp8((int)hw, false);
  float wsel = (lane < 32) ? w0 : w1;
  float acc0 = hv.x * wsel;
  float acc1 = hv.y * wsel;
  float d0 = 0.f, d1 = 0.f;
  int hsel = lane >> 5;
  for (int base = e0; base < e1; base += 64){
    int i = base + lane;
    float e_0 = 0.f, e_1 = 0.f; unsigned sv = 0;
    if (i < e1){
      sv = (unsigned)srcs[i];
      float2 av = AS2[sv];
      e_0 = __expf(lrelu(av.x + adv.x));
      e_1 = __expf(lrelu(av.y + adv.y));
    }
    d0 += e_0; d1 += e_1;
    sbuf[wv][lane] = sv << 7;                 // row byte offset (128 B rows)
    wbuf[wv][0][lane] = e_0;
    wbuf[wv][1][lane] = e_1;
    int cnt = min(64, e1 - base);
    #pragma unroll 8
    for (int j = 0; j < cnt; j++){
      unsigned off = sbuf[wv][j];             // wave-uniform broadcast
      float wss = wbuf[wv][hsel][j];          // 2-address broadcast (free)
      unsigned int hj = *(const unsigned short*)(HB + (off | lane2));
      f32x2 h2 = __builtin_amdgcn_cvt_pk_f32_fp8((int)hj, false);
      acc0 = fmaf(h2.x, wss, acc0);
      acc1 = fmaf(h2.y, wss, acc1);
    }
  }
  #pragma unroll
  for (int o=32;o>0;o>>=1){ d0 += __shfl_xor(d0,o); d1 += __shfl_xor(d1,o); }
  d0 += w0; d1 += w1;
  float dsel = (lane < 32) ? d0 : d1;
  acc0 /= dsel; acc1 /= dsel;
  float o0 = 0.5f*(acc0 + __shfl_xor(acc0, 32));
  float o1 = 0.5f*(acc1 + __shfl_xor(acc1, 32));
  if (lane < 32){
    float vx = o0 + bias[2*lane];
    float vy = o1 + bias[2*lane+1];
    out[(size_t)n*32 + lane] = packbf(vx, vy);
  }
}

// ---- BN stats: per-channel sum / sumsq over bf16 input (256 blocks) ----
__global__ void k_bnstats(const unsigned short* __restrict__ X, float* __restrict__ part, int N){
  int t = threadIdx.x; int c = t & 63; int sub = t >> 6;
  float s = 0.f, s2 = 0.f;
  for (int r = blockIdx.x*4 + sub; r < N; r += gridDim.x*4){
    float v = bf2f(X[(size_t)r*64 + c]);
    s += v; s2 = fmaf(v, v, s2);
  }
  __shared__ float ls[256], lq[256];
  ls[t] = s; lq[t] = s2; __syncthreads();
  if (t < 64){
    s  = ls[t] + ls[t+64] + ls[t+128] + ls[t+192];
    s2 = lq[t] + lq[t+64] + lq[t+128] + lq[t+192];
    atomicAdd(&part[t], s);
    atomicAdd(&part[64+t], s2);
  }
}

// ---- final: gelu(bn(g2)+hmid), pooled sums per batch; bn derived inline ----
__global__ void k_fusepool(const unsigned short* __restrict__ g2, const float* __restrict__ part,
                           const float* __restrict__ gamma, const float* __restrict__ beta,
                           const unsigned short* __restrict__ hmid, const int* __restrict__ batch,
                           float* __restrict__ pool, float* __restrict__ cnt, int N, float invN){
  int t = threadIdx.x; int c = t & 63; int sub = t >> 6;
  int r0 = blockIdx.x*64;
  float mu  = part[c] * invN;
  float var = fmaxf(part[64+c] * invN - mu*mu, 0.f);
  float scale = gamma[c] * rsqrtf(var + 1e-5f);
  float shift = beta[c] - mu*scale;
  float acc = 0.f, ca = 0.f; int curb = -1;
  for (int r = r0 + sub; r < N && r < r0 + 64; r += 4){
    int b = batch[r];
    if (b != curb){
      if (curb >= 0){
        atomicAdd(&pool[curb*64 + c], acc);
        if (c == 0) atomicAdd(&cnt[curb], ca);
      }
      acc = 0.f; ca = 0.f; curb = b;
    }
    float gv = bf2f(g2[(size_t)r*64 + c]);
    float hv = bf2f(hmid[(size_t)r*64 + c]);
    float v = gelu_tanh(fmaf(gv, scale, shift) + hv);
    acc += v; ca += 1.f;
  }
  if (curb >= 0){
    atomicAdd(&pool[curb*64 + c], acc);
    if (c == 0) atomicAdd(&cnt[curb], ca);
  }
}

__global__ void k_out(const float* __restrict__ pool, const float* __restrict__ cnt,
                      float* __restrict__ out, int M){
  int i = blockIdx.x*blockDim.x + threadIdx.x;
  if (i < M) out[i] = pool[i] / fmaxf(cnt[i>>6], 1.f);
}

extern "C" void kernel_launch(void* const* d_in, const int* in_sizes, int n_in,
                              void* d_out, int out_size, void* d_ws, size_t ws_size,
                              hipStream_t stream) {
  const float* x     = (const float*)d_in[0];
  const int*   ei    = (const int*)  d_in[1];
  const int*   batch = (const int*)  d_in[2];
  const float* W1    = (const float*)d_in[3];
  const float* as1   = (const float*)d_in[4];
  const float* ad1   = (const float*)d_in[5];
  const float* b1    = (const float*)d_in[6];
  const float* skW   = (const float*)d_in[7];
  const float* skb   = (const float*)d_in[8];
  const float* gm1   = (const float*)d_in[9];
  const float* bt1   = (const float*)d_in[10];
  const float* W2    = (const float*)d_in[11];
  const float* as2   = (const float*)d_in[12];
  const float* ad2   = (const float*)d_in[13];
  const float* b2    = (const float*)d_in[14];
  const float* gm2   = (const float*)d_in[15];
  const float* bt2   = (const float*)d_in[16];

  int N = in_sizes[2];
  int E = in_sizes[1] / 2;
  const int* esrc = ei;
  const int* edst = ei + E;
  int NB = (N + 127) >> 7;          // 128-node buckets
  float invN = 1.0f / (float)N;

  char* wp = (char*)d_ws;
  size_t off = 0;
  auto alloc = [&](size_t bytes)->void*{
    off = (off + 255) & ~(size_t)255;
    void* p = wp + off;
    off += bytes;
    return p;
  };
  int*   ptr   = (int*)  alloc((size_t)(N+1)*4);
  int*   srcs  = (int*)  alloc((size_t)E*4);
  unsigned int* recs = (unsigned int*)alloc((size_t)E*4);
  int*   boff  = (int*)  alloc(520*4);
  int*   bcur  = (int*)  alloc(512*4);
  unsigned char* hpack = (unsigned char*)alloc((size_t)N*128);    // fp8 H
  float* a_s  = (float*)alloc((size_t)N*2*4);
  float* a_d  = (float*)alloc((size_t)N*2*4);
  unsigned short* gout = (unsigned short*)alloc((size_t)N*64*2);  // bf16 GAT out
  unsigned short* skv  = (unsigned short*)alloc((size_t)N*64*2);  // bf16 x@skipW
  unsigned short* hmid = (unsigned short*)alloc((size_t)N*64*2);  // bf16 layer-1 out
  // zero zone: part1[128] part2[128] pool[4096] cnt[64] bhist[512]
  const int ZN = 128+128+4096+64+512;
  float* zz   = (float*)alloc((size_t)ZN*4);
  float* part1 = zz;
  float* part2 = zz + 128;
  float* pool  = zz + 256;
  float* cnt   = zz + 256 + 4096;
  int*   bhist = (int*)(zz + 256 + 4096 + 64);

  int gg = (N + 127) / 128;

  // zero accumulators
  k_zero<<<(ZN + 255)/256, 256, 0, stream>>>(zz, ZN);

  // CSR build (bucket sort; persistent p_bin to avoid atomic claim chains)
  p_hist<<<256, 256, 0, stream>>>(edst, bhist, E, NB);
  p_scan<<<1, 512, 0, stream>>>(bhist, boff, bcur, ptr, NB, N, E);
  p_bin<<<PBIN_BLOCKS, 512, 0, stream>>>(esrc, edst, bcur, recs, E, NB);
  p_csr<<<NB, 256, 0, stream>>>(recs, boff, ptr, srcs, N);

  // layer 1 (W1 + skip + att fused, MFMA)
  k_gemm3<<<gg, 256, 0, stream>>>(x, W1, skW, as1, ad1, hpack, skv, a_s, a_d, N);
  k_agg<<<(N+3)/4, 256, 0, stream>>>(hpack, a_s, a_d, ptr, srcs, b1, (unsigned int*)gout, N);
  k_bnstats<<<256, 256, 0, stream>>>(gout, part1, N);

  // layer 2: GEMM fused with bn1+skip+gelu (writes hmid)
  k_gemm2f<<<gg, 256, 0, stream>>>(gout, skv, part1, gm1, bt1, skb, W2, as2, ad2,
                                   hpack, hmid, a_s, a_d, N, invN);
  k_agg<<<(N+3)/4, 256, 0, stream>>>(hpack, a_s, a_d, ptr, srcs, b2, (unsigned int*)gout, N);
  k_bnstats<<<256, 256, 0, stream>>>(gout, part2, N);

  // fuse + pool (bn2 derived inline)
  k_fusepool<<<(N+63)/64, 256, 0, stream>>>(gout, part2, gm2, bt2, hmid, batch, pool, cnt, N, invN);
  k_out<<<(out_size + 255)/256, 256, 0, stream>>>(pool, cnt, (float*)d_out, out_size);
}